// Round 2
// baseline (57.669 us; speedup 1.0000x reference)
//
#include <hip/hip_runtime.h>

#define B 4
#define N 1024
#define K 100
#define F 42
#define H 64

#define MFLT (K * F * 3)   // 12600 floats of dfeat per atom
#define MF4  (MFLT / 4)    // 3150 float4 per atom (50400 B, 16B-aligned per atom)
#define CH_F4   768        // float4 per staged chunk (12 KB)
#define CH_PAIRS 1024      // (k,f) pairs per chunk  (768*4/3)
#define NCH 5              // ceil(3150/768); last chunk = 78 f4 = 104 pairs

// ---------------------------------------------------------------------------
// Kernel 1: per-atom MLP forward + analytic input gradient (1 wave / atom).
// ---------------------------------------------------------------------------
__global__ __launch_bounds__(256) void mlp_kernel(
    const float* __restrict__ image,
    const float* __restrict__ W1, const float* __restrict__ b1,
    const float* __restrict__ W2, const float* __restrict__ b2,
    const float* __restrict__ W3, const float* __restrict__ b3,
    float* __restrict__ Ei, float* __restrict__ dE)
{
    __shared__ float xsh[4][F];
    __shared__ float h1sh[4][H];
    __shared__ float aux[4][H];

    const int tid  = threadIdx.x;
    const int lane = tid & 63;
    const int wave = tid >> 6;
    const int atom = blockIdx.x * 4 + wave;

    if (lane < F) xsh[wave][lane] = image[atom * F + lane];
    __syncthreads();

    float a1 = b1[lane];
    #pragma unroll
    for (int f = 0; f < F; ++f) a1 = fmaf(xsh[wave][f], W1[f * H + lane], a1);
    const float h1 = tanhf(a1);
    h1sh[wave][lane] = h1;
    __syncthreads();

    float a2 = b2[lane];
    #pragma unroll 8
    for (int j = 0; j < H; ++j) a2 = fmaf(h1sh[wave][j], W2[j * H + lane], a2);
    const float h2 = tanhf(a2);
    const float w3 = W3[lane];

    float t = h2 * w3;
    #pragma unroll
    for (int off = 32; off > 0; off >>= 1) t += __shfl_down(t, off);
    if (lane == 0) Ei[atom] = t + b3[0];

    aux[wave][lane] = w3 * (1.0f - h2 * h2);
    __syncthreads();

    float s = 0.0f;
    #pragma unroll 8
    for (int j = 0; j < H; ++j) s = fmaf(W2[lane * H + j], aux[wave][j], s);
    const float g1 = s * (1.0f - h1 * h1);
    h1sh[wave][lane] = g1;
    __syncthreads();

    if (lane < F) {
        float dx = 0.0f;
        #pragma unroll 8
        for (int i = 0; i < H; ++i) dx = fmaf(W1[lane * H + i], h1sh[wave][i], dx);
        dE[atom * F + lane] = dx;
    }
}

// ---------------------------------------------------------------------------
// Kernel 2: Etot[b] = sum_n Ei[b,n]  (deterministic fixed-order reduction)
// ---------------------------------------------------------------------------
__global__ __launch_bounds__(256) void etot_kernel(
    const float* __restrict__ Ei, float* __restrict__ Etot)
{
    __shared__ float red[4];
    const int b = blockIdx.x, tid = threadIdx.x;
    float s = 0.0f;
    for (int i = tid; i < N; i += 256) s += Ei[b * N + i];
    #pragma unroll
    for (int off = 32; off > 0; off >>= 1) s += __shfl_down(s, off);
    const int lane = tid & 63, wave = tid >> 6;
    if (lane == 0) red[wave] = s;
    __syncthreads();
    if (tid == 0) Etot[b] = (red[0] + red[1]) + (red[2] + red[3]);
}

// ---------------------------------------------------------------------------
// Kernel 3 (v2): Force via LDS-staged float4 streaming of dfeat.
// One block (256 thr) per atom. dfeat slice (50.4 KB) staged in 12 KB chunks,
// double-buffered: issue float4 loads for chunk c+1, compute chunk c from LDS,
// then ds_write c+1 and ONE sync per iteration.
//  - global loads: lane-contiguous float4 (dwordx4), max bytes/transaction
//  - LDS compute reads: float offsets 3p{,+1,+2}, lane stride 3 -> (3t)%32 is
//    a permutation, 2 lanes/bank = free (m136) -> conflict-free
// ---------------------------------------------------------------------------
__global__ __launch_bounds__(256) void force_kernel(
    const float* __restrict__ dE, const float* __restrict__ dfeat,
    const int* __restrict__ neighbor, float* __restrict__ force)
{
    __shared__ __align__(16) float lds[2][CH_F4 * 4];  // 2 x 12 KB
    __shared__ int   nsh[K];
    __shared__ float red[4][3];

    const int tid = threadIdx.x;
    const int bn  = blockIdx.x;            // b*N + n
    const int b   = bn >> 10;              // N = 1024

    if (tid < K) nsh[tid] = neighbor[bn * K + tid];

    const float4* df4 = (const float4*)dfeat + (size_t)bn * MF4;
    const float*  dEb = dE + (size_t)b * (N * F);

    // prologue: stage chunk 0 (full)
    {
        float4 r0 = df4[tid];
        float4 r1 = df4[256 + tid];
        float4 r2 = df4[512 + tid];
        float4* buf = (float4*)lds[0];
        buf[tid] = r0; buf[256 + tid] = r1; buf[512 + tid] = r2;
    }
    __syncthreads();

    float fx = 0.0f, fy = 0.0f, fz = 0.0f;

    for (int c = 0; c < NCH; ++c) {
        const int cur = c & 1;
        const bool have_next = (c + 1 < NCH);

        // issue next chunk's global loads early (latency hides under compute)
        float4 r0 = {0,0,0,0}, r1 = {0,0,0,0}, r2 = {0,0,0,0};
        if (have_next) {
            const int i0 = (c + 1) * CH_F4 + tid;
            const int i1 = i0 + 256;
            const int i2 = i0 + 512;
            if (i0 < MF4) r0 = df4[i0];
            if (i1 < MF4) r1 = df4[i1];
            if (i2 < MF4) r2 = df4[i2];
        }

        // compute chunk c from LDS
        const float* buf  = lds[cur];
        const int    base = c * CH_PAIRS;
        if (base + CH_PAIRS <= K * F) {
            #pragma unroll
            for (int it = 0; it < CH_PAIRS / 256; ++it) {
                const int p  = it * 256 + tid;
                const int P  = base + p;
                const int k  = P / F;
                const int f  = P - k * F;
                const int nb = nsh[k];
                const float de = (nb > 0) ? dEb[(nb - 1) * F + f] : 0.0f;
                fx = fmaf(de, buf[3 * p + 0], fx);
                fy = fmaf(de, buf[3 * p + 1], fy);
                fz = fmaf(de, buf[3 * p + 2], fz);
            }
        } else {
            const int np = K * F - base;   // 104 on the last chunk
            for (int p = tid; p < np; p += 256) {
                const int P  = base + p;
                const int k  = P / F;
                const int f  = P - k * F;
                const int nb = nsh[k];
                const float de = (nb > 0) ? dEb[(nb - 1) * F + f] : 0.0f;
                fx = fmaf(de, buf[3 * p + 0], fx);
                fy = fmaf(de, buf[3 * p + 1], fy);
                fz = fmaf(de, buf[3 * p + 2], fz);
            }
        }

        // write next chunk into the other buffer, one barrier per iteration
        if (have_next) {
            float4* nbuf = (float4*)lds[cur ^ 1];
            nbuf[tid] = r0; nbuf[256 + tid] = r1; nbuf[512 + tid] = r2;
        }
        __syncthreads();
    }

    #pragma unroll
    for (int off = 32; off > 0; off >>= 1) {
        fx += __shfl_down(fx, off);
        fy += __shfl_down(fy, off);
        fz += __shfl_down(fz, off);
    }
    const int lane = tid & 63, wave = tid >> 6;
    if (lane == 0) { red[wave][0] = fx; red[wave][1] = fy; red[wave][2] = fz; }
    __syncthreads();
    if (tid == 0) {
        force[bn * 3 + 0] = (red[0][0] + red[1][0]) + (red[2][0] + red[3][0]);
        force[bn * 3 + 1] = (red[0][1] + red[1][1]) + (red[2][1] + red[3][1]);
        force[bn * 3 + 2] = (red[0][2] + red[1][2]) + (red[2][2] + red[3][2]);
    }
}

extern "C" void kernel_launch(void* const* d_in, const int* in_sizes, int n_in,
                              void* d_out, int out_size, void* d_ws, size_t ws_size,
                              hipStream_t stream)
{
    const float* image    = (const float*)d_in[0];
    const float* dfeat    = (const float*)d_in[1];
    const int*   neighbor = (const int*)d_in[2];
    // d_in[3] Egroup_weight, d_in[4] divider: unused by the reference outputs
    const float* W1 = (const float*)d_in[5];
    const float* b1 = (const float*)d_in[6];
    const float* W2 = (const float*)d_in[7];
    const float* b2 = (const float*)d_in[8];
    const float* W3 = (const float*)d_in[9];
    const float* b3 = (const float*)d_in[10];

    float* out   = (float*)d_out;
    float* Etot  = out;                 // [B]
    float* Ei    = out + B;             // [B,N]
    float* Force = out + B + B * N;     // [B,N,3]
    float* dE    = (float*)d_ws;        // [B,N,F] = 688,128 bytes

    mlp_kernel<<<(B * N) / 4, 256, 0, stream>>>(image, W1, b1, W2, b2, W3, b3, Ei, dE);
    etot_kernel<<<B, 256, 0, stream>>>(Ei, Etot);
    force_kernel<<<B * N, 256, 0, stream>>>(dE, dfeat, neighbor, Force);
}